// Round 2
// baseline (406.880 us; speedup 1.0000x reference)
//
#include <hip/hip_runtime.h>

typedef __bf16 bf16;
typedef __bf16 bf16x8_t __attribute__((ext_vector_type(8)));
typedef __bf16 bf16x4_t __attribute__((ext_vector_type(4)));
typedef float f32x4_t __attribute__((ext_vector_type(4)));

#define S_ 2048
#define E_ 1024
#define HD 64
#define LOG2E 1.4426950408889634f
#define QSCALE (0.125f * LOG2E)   // 1/sqrt(64) * log2(e), folded into Q

// async global->LDS, 16B per lane; LDS dest is wave-uniform base + lane*16
__device__ __forceinline__ void gl_lds16(const bf16* g, bf16* l) {
  __builtin_amdgcn_global_load_lds(
      (const __attribute__((address_space(1))) unsigned int*)g,
      (__attribute__((address_space(3))) unsigned int*)l, 16, 0, 0);
}

__device__ __forceinline__ f32x4_t vmax4(f32x4_t a, f32x4_t b) {
  f32x4_t r;
  r[0] = fmaxf(a[0], b[0]); r[1] = fmaxf(a[1], b[1]);
  r[2] = fmaxf(a[2], b[2]); r[3] = fmaxf(a[3], b[3]);
  return r;
}

// ---------- fp32 -> bf16 convert (x) ----------
__global__ void cvt4(const float* __restrict__ in, bf16* __restrict__ out) {
  int i = (blockIdx.x * 256 + threadIdx.x) * 4;
  float4 v = *(const float4*)(in + i);
  bf16x4_t o = { (bf16)v.x, (bf16)v.y, (bf16)v.z, (bf16)v.w };
  *(bf16x4_t*)(out + i) = o;
}

// ---------- fp32 [R][C] -> bf16 [C][R] (weights) ----------
__global__ void transpose_cvt(const float* __restrict__ in, bf16* __restrict__ out,
                              int R, int C) {
  __shared__ float tile[32][33];
  int c0 = blockIdx.x * 32, r0 = blockIdx.y * 32;
  int tx = threadIdx.x & 31, ty = threadIdx.x >> 5;
#pragma unroll
  for (int i = 0; i < 32; i += 8)
    tile[ty + i][tx] = in[(size_t)(r0 + ty + i) * C + c0 + tx];
  __syncthreads();
#pragma unroll
  for (int i = 0; i < 32; i += 8)
    out[(size_t)(c0 + ty + i) * R + r0 + tx] = (bf16)tile[tx][ty + i];
}

// ---------- 128x128-tile GEMM, BK=64, global_load_lds staging, XOR-swizzled LDS ----
// MODE 0: QKV epilogue (scatter to Q scaled, K, Vt transposed). MODE 1: proj fp32 out.
template <int MODE>
__global__ __launch_bounds__(256, 2)
void gemm128(const bf16* __restrict__ A, const bf16* __restrict__ Bt,
             const float* __restrict__ bias,
             bf16* __restrict__ Q, bf16* __restrict__ K, bf16* __restrict__ Vt,
             float* __restrict__ Out) {
  __shared__ __align__(16) bf16 As[128 * 64];
  __shared__ __align__(16) bf16 Bs[128 * 64];
  const int tid = threadIdx.x;
  const int wave = tid >> 6, lane = tid & 63;
  const int quad = lane >> 4, l16 = lane & 15;
  const int wm = wave >> 1, wn = wave & 1;
  const int bm = blockIdx.x, bn = blockIdx.y;

  f32x4_t acc[4][4];
#pragma unroll
  for (int i = 0; i < 4; i++)
#pragma unroll
    for (int j = 0; j < 4; j++) acc[i][j] = (f32x4_t){0.f, 0.f, 0.f, 0.f};

  for (int k0 = 0; k0 < 1024; k0 += 64) {
    __syncthreads();
    // stage 16KB A + 16KB B; swizzle source so LDS chunk (row, c) holds
    // global chunk (row, c ^ (row&7)) -> reads are 2-way max
#pragma unroll
    for (int it = 0; it < 4; it++) {
      int id = it * 256 + tid;
      int row = id >> 3, c = id & 7;
      int sc = (c ^ (row & 7)) * 8;
      gl_lds16(A + (size_t)(bm * 128 + row) * 1024 + k0 + sc, As + id * 8);
      gl_lds16(Bt + (size_t)(bn * 128 + row) * 1024 + k0 + sc, Bs + id * 8);
    }
    __syncthreads();
#pragma unroll
    for (int ks = 0; ks < 2; ks++) {
      bf16x8_t af[4], bfr[4];
#pragma unroll
      for (int i = 0; i < 4; i++) {
        int row = wm * 64 + i * 16 + l16;
        af[i] = *(const bf16x8_t*)&As[row * 64 + (((ks * 4 + quad) ^ (row & 7)) * 8)];
      }
#pragma unroll
      for (int j = 0; j < 4; j++) {
        int row = wn * 64 + j * 16 + l16;
        bfr[j] = *(const bf16x8_t*)&Bs[row * 64 + (((ks * 4 + quad) ^ (row & 7)) * 8)];
      }
#pragma unroll
      for (int i = 0; i < 4; i++)
#pragma unroll
        for (int j = 0; j < 4; j++)
          acc[i][j] = __builtin_amdgcn_mfma_f32_16x16x32_bf16(af[i], bfr[j], acc[i][j], 0, 0, 0);
    }
  }

  if (MODE == 0) {
    // n decides q/k/v. Q: [bh][s][64] scaled by QSCALE. K: [bh][s][64]. V: [bh][64][s].
#pragma unroll
    for (int j = 0; j < 4; j++) {
      int n_g = bn * 128 + wn * 64 + j * 16 + l16;
      float bv = bias[n_g];
      int which = n_g >> 10;
      int cc = n_g & 1023;
      int hh = cc >> 6, dd = cc & 63;
#pragma unroll
      for (int i = 0; i < 4; i++) {
        int m0 = bm * 128 + wm * 64 + i * 16 + quad * 4;
        int bb = m0 >> 11, ss0 = m0 & 2047;
        int bhn = bb * 16 + hh;
        if (which == 2) {
          bf16x4_t pk;
#pragma unroll
          for (int r = 0; r < 4; r++) pk[r] = (bf16)(acc[i][j][r] + bv);
          *(bf16x4_t*)&Vt[((size_t)bhn * 64 + dd) * 2048 + ss0] = pk;
        } else {
          bf16* dst = (which == 0) ? Q : K;
          float scl = (which == 0) ? QSCALE : 1.f;
#pragma unroll
          for (int r = 0; r < 4; r++)
            dst[((size_t)bhn * 2048 + ss0 + r) * 64 + dd] = (bf16)((acc[i][j][r] + bv) * scl);
        }
      }
    }
  } else {
#pragma unroll
    for (int j = 0; j < 4; j++) {
      int n_g = bn * 128 + wn * 64 + j * 16 + l16;
      float bv = bias[n_g];
#pragma unroll
      for (int i = 0; i < 4; i++) {
        int m0 = bm * 128 + wm * 64 + i * 16 + quad * 4;
#pragma unroll
        for (int r = 0; r < 4; r++)
          Out[(size_t)(m0 + r) * 1024 + n_g] = acc[i][j][r] + bv;
      }
    }
  }
}

// ---------- Flash attention, S^T formulation, occupancy-first ----------
// Grid 16x64: block (pid,bh) handles q-block pid alone (pid+1 k-iters) -> 1024
// blocks, 4 blocks/CU co-resident (16 waves/CU). LDS cut to 32KB: single-buffered
// K,V; P scratch reuses the DEAD K tile after QK (barrier C guards the handoff).
// Staging stall is hidden by cross-block TLP (m114 model), not source pipelining.
// Wave owns 32 q rows. S^T = K·Q^T; softmax rows in-lane (tree-reduced) + 2
// shuffles. PV: O^T = Vt·P^T. All LDS chunk-XOR-swizzled.
__global__ __launch_bounds__(256, 4)
void attn_kernel(const bf16* __restrict__ Q, const bf16* __restrict__ K,
                 const bf16* __restrict__ Vt, bf16* __restrict__ O) {
  __shared__ __align__(16) bf16 Ks[128 * 64];  // [k][d] 16KB; becomes P after QK
  __shared__ __align__(16) bf16 Vs[64 * 128];  // [d][s] 16KB
  const int tid = threadIdx.x;
  const int wave = tid >> 6, lane = tid & 63;
  const int quad = lane >> 4, l16 = lane & 15;
  const int qb = blockIdx.x, bh = blockIdx.y;
  const int b = bh >> 4, h = bh & 15;

  const bf16* Qg = Q + (size_t)bh * S_ * HD;
  const bf16* Kg = K + (size_t)bh * S_ * HD;
  const bf16* Vg = Vt + (size_t)bh * HD * S_;
  bf16* Pw = Ks + wave * 2048;  // 32x64 wave slice of the dead K tile

  // Q fragments (B-operand): n = q row (l16), k = d
  bf16x8_t qf[2][2];
#pragma unroll
  for (int ni = 0; ni < 2; ni++)
#pragma unroll
    for (int ks = 0; ks < 2; ks++)
      qf[ni][ks] = *(const bf16x8_t*)(Qg +
          (size_t)(qb * 128 + wave * 32 + ni * 16 + l16) * HD + ks * 32 + quad * 8);

  f32x4_t o[4][2];
#pragma unroll
  for (int mi = 0; mi < 4; mi++)
#pragma unroll
    for (int ni = 0; ni < 2; ni++) o[mi][ni] = (f32x4_t){0.f, 0.f, 0.f, 0.f};
  float m_[2] = {-1e30f, -1e30f}, l_[2] = {0.f, 0.f};

  for (int kb = 0; kb <= qb; kb++) {
    __syncthreads();  // A: prior iter's PV (V + P) reads done in all waves
#pragma unroll
    for (int it = 0; it < 4; it++) {
      int id = it * 256 + tid;
      {
        int row = id >> 3, cc = id & 7;
        gl_lds16(Kg + (size_t)kb * 128 * HD + row * 64 + ((cc ^ (row & 7)) * 8),
                 Ks + id * 8);
      }
      {
        int d = id >> 4, cc = id & 15;
        gl_lds16(Vg + (size_t)d * S_ + kb * 128 + ((cc ^ (d & 7)) * 8), Vs + id * 8);
      }
    }
    __syncthreads();  // B: staging complete (implicit vmcnt(0))

    // S^T = K · Q^T : lane holds S^T[k = mi*16+quad*4+r][q = ni*16+l16]
    f32x4_t sacc[8][2];
#pragma unroll
    for (int mi = 0; mi < 8; mi++)
#pragma unroll
      for (int ni = 0; ni < 2; ni++) sacc[mi][ni] = (f32x4_t){0.f, 0.f, 0.f, 0.f};
    __builtin_amdgcn_s_setprio(1);
#pragma unroll
    for (int ks = 0; ks < 2; ks++)
#pragma unroll
      for (int mi = 0; mi < 8; mi++) {
        int kr = mi * 16 + l16;
        bf16x8_t kf = *(const bf16x8_t*)&Ks[kr * 64 + (((ks * 4 + quad) ^ (kr & 7)) * 8)];
        sacc[mi][0] = __builtin_amdgcn_mfma_f32_16x16x32_bf16(kf, qf[0][ks], sacc[mi][0], 0, 0, 0);
        sacc[mi][1] = __builtin_amdgcn_mfma_f32_16x16x32_bf16(kf, qf[1][ks], sacc[mi][1], 0, 0, 0);
      }
    __builtin_amdgcn_s_setprio(0);

    if (kb == qb) {  // causal mask, block-local
#pragma unroll
      for (int mi = 0; mi < 8; mi++)
#pragma unroll
        for (int ni = 0; ni < 2; ni++) {
          int qrow = wave * 32 + ni * 16 + l16;
          int krow = mi * 16 + quad * 4;
#pragma unroll
          for (int r = 0; r < 4; r++)
            if (krow + r > qrow) sacc[mi][ni][r] = -1e30f;
        }
    }

    // online softmax (base-2; scale folded into Q). Tree-reduced in-lane stats
    // (dep depth ~7 vs 31) + 2 shuffles.
#pragma unroll
    for (int ni = 0; ni < 2; ni++) {
      f32x4_t t0 = vmax4(sacc[0][ni], sacc[1][ni]);
      f32x4_t t1 = vmax4(sacc[2][ni], sacc[3][ni]);
      f32x4_t t2 = vmax4(sacc[4][ni], sacc[5][ni]);
      f32x4_t t3 = vmax4(sacc[6][ni], sacc[7][ni]);
      t0 = vmax4(t0, t1); t2 = vmax4(t2, t3); t0 = vmax4(t0, t2);
      float mx = fmaxf(fmaxf(t0[0], t0[1]), fmaxf(t0[2], t0[3]));
      mx = fmaxf(mx, __shfl_xor(mx, 16));
      mx = fmaxf(mx, __shfl_xor(mx, 32));
      float mnew = fmaxf(m_[ni], mx);
      float alpha = __builtin_amdgcn_exp2f(m_[ni] - mnew);
      m_[ni] = mnew;
      f32x4_t a0 = {0.f, 0.f, 0.f, 0.f}, a1 = {0.f, 0.f, 0.f, 0.f};
#pragma unroll
      for (int mi = 0; mi < 4; mi++) {
#pragma unroll
        for (int r = 0; r < 4; r++) {
          sacc[mi][ni][r] = __builtin_amdgcn_exp2f(sacc[mi][ni][r] - mnew);
          sacc[mi + 4][ni][r] = __builtin_amdgcn_exp2f(sacc[mi + 4][ni][r] - mnew);
        }
        a0 += sacc[mi][ni];
        a1 += sacc[mi + 4][ni];
      }
      a0 += a1;
      float rs = (a0[0] + a0[1]) + (a0[2] + a0[3]);
      rs += __shfl_xor(rs, 16);
      rs += __shfl_xor(rs, 32);
      l_[ni] = alpha * l_[ni] + rs;
#pragma unroll
      for (int mi = 0; mi < 4; mi++)
#pragma unroll
        for (int r = 0; r < 4; r++) o[mi][ni][r] *= alpha;
    }

    __syncthreads();  // C: all waves done reading Ks -> reusable as P scratch

    // PV in two k-halves through the 32x64 wave-private P slice (in dead Ks):
    // write P[q][kloc] for mi in {4hh..4hh+3}, then O^T += Vt·P^T for that half.
    // Wave-private LDS + in-order DS pipe -> no barrier between halves.
#pragma unroll
    for (int hh = 0; hh < 2; hh++) {
#pragma unroll
      for (int ni = 0; ni < 2; ni++) {
        int qr = ni * 16 + l16;
#pragma unroll
        for (int mm = 0; mm < 4; mm++) {
          bf16x4_t pk;
#pragma unroll
          for (int r = 0; r < 4; r++) pk[r] = (bf16)sacc[hh * 4 + mm][ni][r];
          int c = mm * 2 + (quad >> 1);
          *(bf16x4_t*)&Pw[qr * 64 + ((c ^ (qr & 7)) * 8) + (quad & 1) * 4] = pk;
        }
      }
#pragma unroll
      for (int k2 = 0; k2 < 2; k2++) {
        int ks2 = hh * 2 + k2;
        bf16x8_t vb[4], pa[2];
#pragma unroll
        for (int mi = 0; mi < 4; mi++) {
          int d = mi * 16 + l16;
          vb[mi] = *(const bf16x8_t*)&Vs[d * 128 + (((ks2 * 4 + quad) ^ (d & 7)) * 8)];
        }
#pragma unroll
        for (int ni = 0; ni < 2; ni++) {
          int qr = ni * 16 + l16;
          pa[ni] = *(const bf16x8_t*)&Pw[qr * 64 + (((k2 * 4 + quad) ^ (qr & 7)) * 8)];
        }
        __builtin_amdgcn_s_setprio(1);
#pragma unroll
        for (int mi = 0; mi < 4; mi++)
#pragma unroll
          for (int ni = 0; ni < 2; ni++)
            o[mi][ni] = __builtin_amdgcn_mfma_f32_16x16x32_bf16(vb[mi], pa[ni], o[mi][ni], 0, 0, 0);
        __builtin_amdgcn_s_setprio(0);
      }
    }
  }

  // epilogue: O^T lane layout -> O[b][s][h*64+d], packed 4 consecutive d
#pragma unroll
  for (int ni = 0; ni < 2; ni++) {
    float inv = 1.0f / l_[ni];
    int q_g = qb * 128 + wave * 32 + ni * 16 + l16;
    size_t rowb = (size_t)(b * S_ + q_g) * E_ + h * HD;
#pragma unroll
    for (int mi = 0; mi < 4; mi++) {
      bf16x4_t ov;
#pragma unroll
      for (int r = 0; r < 4; r++) ov[r] = (bf16)(o[mi][ni][r] * inv);
      *(bf16x4_t*)&O[rowb + mi * 16 + quad * 4] = ov;
    }
  }
}

extern "C" void kernel_launch(void* const* d_in, const int* in_sizes, int n_in,
                              void* d_out, int out_size, void* d_ws, size_t ws_size,
                              hipStream_t stream) {
  const float* x      = (const float*)d_in[0];
  const float* W_attn = (const float*)d_in[1];
  const float* b_attn = (const float*)d_in[2];
  const float* W_proj = (const float*)d_in[3];
  const float* b_proj = (const float*)d_in[4];
  float* out = (float*)d_out;

  // workspace (bf16 elems), ~75.5 MB total
  bf16* xb  = (bf16*)d_ws;            // 8192*1024
  bf16* Wat = xb + 8388608ull;        // 3072*1024 (W_attn^T)
  bf16* Wpt = Wat + 3145728ull;       // 1024*1024 (W_proj^T)
  bf16* Qb  = Wpt + 1048576ull;       // [B,H,S,64], pre-scaled by QSCALE
  bf16* Kb  = Qb + 8388608ull;        // [B,H,S,64]
  bf16* Vtb = Kb + 8388608ull;        // [B,H,64,S] (written transposed by QKV epilogue)
  bf16* AOb = xb;                     // alias: x dead after QKV GEMM

  cvt4<<<8192, 256, 0, stream>>>(x, xb);
  transpose_cvt<<<dim3(96, 32), 256, 0, stream>>>(W_attn, Wat, 1024, 3072);
  transpose_cvt<<<dim3(32, 32), 256, 0, stream>>>(W_proj, Wpt, 1024, 1024);
  gemm128<0><<<dim3(64, 24), 256, 0, stream>>>(xb, Wat, b_attn, Qb, Kb, Vtb, nullptr);
  attn_kernel<<<dim3(16, 64), 256, 0, stream>>>(Qb, Kb, Vtb, AOb);
  gemm128<1><<<dim3(64, 8), 256, 0, stream>>>(AOb, Wpt, b_proj, nullptr, nullptr, nullptr, out);
}

// Round 3
// 246.945 us; speedup vs baseline: 1.6477x; 1.6477x over previous
//
#include <hip/hip_runtime.h>

typedef __bf16 bf16;
typedef __bf16 bf16x8_t __attribute__((ext_vector_type(8)));
typedef __bf16 bf16x4_t __attribute__((ext_vector_type(4)));
typedef float f32x4_t __attribute__((ext_vector_type(4)));

#define S_ 2048
#define E_ 1024
#define HD 64
#define LOG2E 1.4426950408889634f
#define QSCALE (0.125f * LOG2E)   // 1/sqrt(64) * log2(e), folded into Q
#define DEFER_THR 8.0f            // base-2 domain: P bounded by 2^8=256

// async global->LDS, 16B per lane; LDS dest is wave-uniform base + lane*16
__device__ __forceinline__ void gl_lds16(const bf16* g, bf16* l) {
  __builtin_amdgcn_global_load_lds(
      (const __attribute__((address_space(1))) unsigned int*)g,
      (__attribute__((address_space(3))) unsigned int*)l, 16, 0, 0);
}

__device__ __forceinline__ f32x4_t vmax4(f32x4_t a, f32x4_t b) {
  f32x4_t r;
  r[0] = fmaxf(a[0], b[0]); r[1] = fmaxf(a[1], b[1]);
  r[2] = fmaxf(a[2], b[2]); r[3] = fmaxf(a[3], b[3]);
  return r;
}

// ---------- fp32 -> bf16 convert (x) ----------
__global__ void cvt4(const float* __restrict__ in, bf16* __restrict__ out) {
  int i = (blockIdx.x * 256 + threadIdx.x) * 4;
  float4 v = *(const float4*)(in + i);
  bf16x4_t o = { (bf16)v.x, (bf16)v.y, (bf16)v.z, (bf16)v.w };
  *(bf16x4_t*)(out + i) = o;
}

// ---------- fp32 [R][C] -> bf16 [C][R] (weights) ----------
__global__ void transpose_cvt(const float* __restrict__ in, bf16* __restrict__ out,
                              int R, int C) {
  __shared__ float tile[32][33];
  int c0 = blockIdx.x * 32, r0 = blockIdx.y * 32;
  int tx = threadIdx.x & 31, ty = threadIdx.x >> 5;
#pragma unroll
  for (int i = 0; i < 32; i += 8)
    tile[ty + i][tx] = in[(size_t)(r0 + ty + i) * C + c0 + tx];
  __syncthreads();
#pragma unroll
  for (int i = 0; i < 32; i += 8)
    out[(size_t)(c0 + ty + i) * R + r0 + tx] = (bf16)tile[tx][ty + i];
}

// ---------- 128x128-tile GEMM, BK=64, global_load_lds staging, XOR-swizzled LDS ----
// MODE 0: QKV epilogue (scatter to Q scaled, K, Vt transposed). MODE 1: proj fp32 out.
template <int MODE>
__global__ __launch_bounds__(256, 2)
void gemm128(const bf16* __restrict__ A, const bf16* __restrict__ Bt,
             const float* __restrict__ bias,
             bf16* __restrict__ Q, bf16* __restrict__ K, bf16* __restrict__ Vt,
             float* __restrict__ Out) {
  __shared__ __align__(16) bf16 As[128 * 64];
  __shared__ __align__(16) bf16 Bs[128 * 64];
  const int tid = threadIdx.x;
  const int wave = tid >> 6, lane = tid & 63;
  const int quad = lane >> 4, l16 = lane & 15;
  const int wm = wave >> 1, wn = wave & 1;
  const int bm = blockIdx.x, bn = blockIdx.y;

  f32x4_t acc[4][4];
#pragma unroll
  for (int i = 0; i < 4; i++)
#pragma unroll
    for (int j = 0; j < 4; j++) acc[i][j] = (f32x4_t){0.f, 0.f, 0.f, 0.f};

  for (int k0 = 0; k0 < 1024; k0 += 64) {
    __syncthreads();
    // stage 16KB A + 16KB B; swizzle source so LDS chunk (row, c) holds
    // global chunk (row, c ^ (row&7)) -> reads are 2-way max
#pragma unroll
    for (int it = 0; it < 4; it++) {
      int id = it * 256 + tid;
      int row = id >> 3, c = id & 7;
      int sc = (c ^ (row & 7)) * 8;
      gl_lds16(A + (size_t)(bm * 128 + row) * 1024 + k0 + sc, As + id * 8);
      gl_lds16(Bt + (size_t)(bn * 128 + row) * 1024 + k0 + sc, Bs + id * 8);
    }
    __syncthreads();
#pragma unroll
    for (int ks = 0; ks < 2; ks++) {
      bf16x8_t af[4], bfr[4];
#pragma unroll
      for (int i = 0; i < 4; i++) {
        int row = wm * 64 + i * 16 + l16;
        af[i] = *(const bf16x8_t*)&As[row * 64 + (((ks * 4 + quad) ^ (row & 7)) * 8)];
      }
#pragma unroll
      for (int j = 0; j < 4; j++) {
        int row = wn * 64 + j * 16 + l16;
        bfr[j] = *(const bf16x8_t*)&Bs[row * 64 + (((ks * 4 + quad) ^ (row & 7)) * 8)];
      }
#pragma unroll
      for (int i = 0; i < 4; i++)
#pragma unroll
        for (int j = 0; j < 4; j++)
          acc[i][j] = __builtin_amdgcn_mfma_f32_16x16x32_bf16(af[i], bfr[j], acc[i][j], 0, 0, 0);
    }
  }

  if (MODE == 0) {
    // n decides q/k/v. Q: [bh][s][64] scaled by QSCALE. K: [bh][s][64]. V: [bh][64][s].
#pragma unroll
    for (int j = 0; j < 4; j++) {
      int n_g = bn * 128 + wn * 64 + j * 16 + l16;
      float bv = bias[n_g];
      int which = n_g >> 10;
      int cc = n_g & 1023;
      int hh = cc >> 6, dd = cc & 63;
#pragma unroll
      for (int i = 0; i < 4; i++) {
        int m0 = bm * 128 + wm * 64 + i * 16 + quad * 4;
        int bb = m0 >> 11, ss0 = m0 & 2047;
        int bhn = bb * 16 + hh;
        if (which == 2) {
          bf16x4_t pk;
#pragma unroll
          for (int r = 0; r < 4; r++) pk[r] = (bf16)(acc[i][j][r] + bv);
          *(bf16x4_t*)&Vt[((size_t)bhn * 64 + dd) * 2048 + ss0] = pk;
        } else {
          bf16* dst = (which == 0) ? Q : K;
          float scl = (which == 0) ? QSCALE : 1.f;
#pragma unroll
          for (int r = 0; r < 4; r++)
            dst[((size_t)bhn * 2048 + ss0 + r) * 64 + dd] = (bf16)((acc[i][j][r] + bv) * scl);
        }
      }
    }
  } else {
#pragma unroll
    for (int j = 0; j < 4; j++) {
      int n_g = bn * 128 + wn * 64 + j * 16 + l16;
      float bv = bias[n_g];
#pragma unroll
      for (int i = 0; i < 4; i++) {
        int m0 = bm * 128 + wm * 64 + i * 16 + quad * 4;
#pragma unroll
        for (int r = 0; r < 4; r++)
          Out[(size_t)(m0 + r) * 1024 + n_g] = acc[i][j][r] + bv;
      }
    }
  }
}

// ---------- Flash attention, S^T formulation, software-pipelined ----------
// Round-1 structure (74.8us, no spill): 4 waves, K/V double-buffered in 80KB
// dynamic LDS (2 blocks/CU), stage(kb+1) issued BEFORE compute(kb), single
// __syncthreads per tile. Wave owns 32 q rows; S^T = K*Q^T; PV: O^T = Vt*P^T
// through a 32x64 wave-private P slice (two k-halves). All LDS chunk-XOR-swizzled.
// Round-3 additions (local, same register/LDS envelope):
//  - T5: s_setprio(1) around QK and PV MFMA clusters (+4-7% attn, m191)
//  - T13: defer-max with THR=8 (base-2); skips o-rescale + alpha chain (+5%, m214)
//  - V ds_reads hoisted before P ds_writes (independent LDS work while P drains)
__global__ __launch_bounds__(256, 2)
void attn_kernel(const bf16* __restrict__ Q, const bf16* __restrict__ K,
                 const bf16* __restrict__ Vt, bf16* __restrict__ O) {
  extern __shared__ __align__(16) bf16 smem[];
  bf16* Ks = smem;              // [2][128*64]  2x16KB  [k][d] swizzled
  bf16* Vs = smem + 16384;      // [2][64*128]  2x16KB  [d][s] swizzled
  bf16* Ps = smem + 32768;      // [4][32*64]   16KB    per-wave P[q][kloc] swizzled
  const int tid = threadIdx.x;
  const int wave = tid >> 6, lane = tid & 63;
  const int quad = lane >> 4, l16 = lane & 15;
  const int pid = blockIdx.x, bh = blockIdx.y;
  const int b = bh >> 4, h = bh & 15;

  const bf16* Qg = Q + (size_t)bh * S_ * HD;
  const bf16* Kg = K + (size_t)bh * S_ * HD;
  const bf16* Vg = Vt + (size_t)bh * HD * S_;
  bf16* Pw = Ps + wave * 2048;

  auto stage = [&](int c, int kb) {
    const bf16* Ksrc = Kg + (size_t)kb * 128 * HD;
    const bf16* Vsrc = Vg + kb * 128;
    bf16* Kd = Ks + c * 8192;
    bf16* Vd = Vs + c * 8192;
#pragma unroll
    for (int it = 0; it < 4; it++) {
      int id = it * 256 + tid;
      {
        int row = id >> 3, cc = id & 7;
        gl_lds16(Ksrc + row * 64 + ((cc ^ (row & 7)) * 8), Kd + id * 8);
      }
      {
        int d = id >> 4, cc = id & 15;
        gl_lds16(Vsrc + (size_t)d * S_ + ((cc ^ (d & 7)) * 8), Vd + id * 8);
      }
    }
  };

  int cur = 0;
  stage(0, 0);  // prologue: tile 0

  for (int qi = 0; qi < 2; qi++) {
    const int qb = qi ? (15 - pid) : pid;
    // Q fragments (B-operand): n = q row (l16), k = d
    bf16x8_t qf[2][2];
#pragma unroll
    for (int ni = 0; ni < 2; ni++)
#pragma unroll
      for (int ks = 0; ks < 2; ks++)
        qf[ni][ks] = *(const bf16x8_t*)(Qg +
            (size_t)(qb * 128 + wave * 32 + ni * 16 + l16) * HD + ks * 32 + quad * 8);

    f32x4_t o[4][2];
#pragma unroll
    for (int mi = 0; mi < 4; mi++)
#pragma unroll
      for (int ni = 0; ni < 2; ni++) o[mi][ni] = (f32x4_t){0.f, 0.f, 0.f, 0.f};
    float m_[2] = {-1e30f, -1e30f}, l_[2] = {0.f, 0.f};

    if (qi == 0) __syncthreads();  // prologue stage complete (qi=1's tile 0 is
                                   // covered by qi=0's last end-of-iter barrier)

    for (int kb = 0; kb <= qb; kb++) {
      // issue next tile's loads FIRST -> in flight under the whole compute phase
      if (kb < qb) stage(cur ^ 1, kb + 1);
      else if (qi == 0) stage(cur ^ 1, 0);  // prefetch qi=1's tile 0 (qb-independent)

      const bf16* Kc = Ks + cur * 8192;
      const bf16* Vc = Vs + cur * 8192;

      // S^T = K · Q^T : lane holds S^T[k = mi*16+quad*4+r][q = ni*16+l16]
      f32x4_t sacc[8][2];
#pragma unroll
      for (int mi = 0; mi < 8; mi++)
#pragma unroll
        for (int ni = 0; ni < 2; ni++) sacc[mi][ni] = (f32x4_t){0.f, 0.f, 0.f, 0.f};
      __builtin_amdgcn_s_setprio(1);
#pragma unroll
      for (int ks = 0; ks < 2; ks++)
#pragma unroll
        for (int mi = 0; mi < 8; mi++) {
          int kr = mi * 16 + l16;
          bf16x8_t kf = *(const bf16x8_t*)&Kc[kr * 64 + (((ks * 4 + quad) ^ (kr & 7)) * 8)];
          sacc[mi][0] = __builtin_amdgcn_mfma_f32_16x16x32_bf16(kf, qf[0][ks], sacc[mi][0], 0, 0, 0);
          sacc[mi][1] = __builtin_amdgcn_mfma_f32_16x16x32_bf16(kf, qf[1][ks], sacc[mi][1], 0, 0, 0);
        }
      __builtin_amdgcn_s_setprio(0);

      if (kb == qb) {  // causal mask, block-local
#pragma unroll
        for (int mi = 0; mi < 8; mi++)
#pragma unroll
          for (int ni = 0; ni < 2; ni++) {
            int qrow = wave * 32 + ni * 16 + l16;
            int krow = mi * 16 + quad * 4;
#pragma unroll
            for (int r = 0; r < 4; r++)
              if (krow + r > qrow) sacc[mi][ni][r] = -1e30f;
          }
      }

      // online softmax (base-2; scale folded into Q). Tree-reduced in-lane stats
      // + 2 shuffles. T13 defer-max: if no row grew past m_old+THR (wave-uniform
      // check), keep m_old -> no alpha exp2, no o-rescale.
#pragma unroll
      for (int ni = 0; ni < 2; ni++) {
        f32x4_t t0 = vmax4(sacc[0][ni], sacc[1][ni]);
        f32x4_t t1 = vmax4(sacc[2][ni], sacc[3][ni]);
        f32x4_t t2 = vmax4(sacc[4][ni], sacc[5][ni]);
        f32x4_t t3 = vmax4(sacc[6][ni], sacc[7][ni]);
        t0 = vmax4(t0, t1); t2 = vmax4(t2, t3); t0 = vmax4(t0, t2);
        float mx = fmaxf(fmaxf(t0[0], t0[1]), fmaxf(t0[2], t0[3]));
        mx = fmaxf(mx, __shfl_xor(mx, 16));
        mx = fmaxf(mx, __shfl_xor(mx, 32));
        float mref = m_[ni];
        if (__all(mx <= mref + DEFER_THR)) {
          // deferred: P = exp2(S - m_old), bounded by 2^THR; alpha == 1
          f32x4_t a0 = {0.f, 0.f, 0.f, 0.f}, a1 = {0.f, 0.f, 0.f, 0.f};
#pragma unroll
          for (int mi = 0; mi < 4; mi++) {
#pragma unroll
            for (int r = 0; r < 4; r++) {
              sacc[mi][ni][r] = __builtin_amdgcn_exp2f(sacc[mi][ni][r] - mref);
              sacc[mi + 4][ni][r] = __builtin_amdgcn_exp2f(sacc[mi + 4][ni][r] - mref);
            }
            a0 += sacc[mi][ni];
            a1 += sacc[mi + 4][ni];
          }
          a0 += a1;
          float rs = (a0[0] + a0[1]) + (a0[2] + a0[3]);
          rs += __shfl_xor(rs, 16);
          rs += __shfl_xor(rs, 32);
          l_[ni] += rs;
        } else {
          float mnew = fmaxf(mref, mx);
          float alpha = __builtin_amdgcn_exp2f(mref - mnew);
          m_[ni] = mnew;
          f32x4_t a0 = {0.f, 0.f, 0.f, 0.f}, a1 = {0.f, 0.f, 0.f, 0.f};
#pragma unroll
          for (int mi = 0; mi < 4; mi++) {
#pragma unroll
            for (int r = 0; r < 4; r++) {
              sacc[mi][ni][r] = __builtin_amdgcn_exp2f(sacc[mi][ni][r] - mnew);
              sacc[mi + 4][ni][r] = __builtin_amdgcn_exp2f(sacc[mi + 4][ni][r] - mnew);
            }
            a0 += sacc[mi][ni];
            a1 += sacc[mi + 4][ni];
          }
          a0 += a1;
          float rs = (a0[0] + a0[1]) + (a0[2] + a0[3]);
          rs += __shfl_xor(rs, 16);
          rs += __shfl_xor(rs, 32);
          l_[ni] = alpha * l_[ni] + rs;
#pragma unroll
          for (int mi = 0; mi < 4; mi++)
#pragma unroll
            for (int r = 0; r < 4; r++) o[mi][ni][r] *= alpha;
        }
      }

      // PV in two k-halves through the 32x64 wave-private P buffer. Per half:
      // V reads hoisted first (independent), then P writes, then P reads + MFMA.
      // Wave-private LDS + in-order DS pipe -> no barriers.
#pragma unroll
      for (int hh = 0; hh < 2; hh++) {
        bf16x8_t vb[2][4];
#pragma unroll
        for (int k2 = 0; k2 < 2; k2++) {
          int ks2 = hh * 2 + k2;
#pragma unroll
          for (int mi = 0; mi < 4; mi++) {
            int d = mi * 16 + l16;
            vb[k2][mi] = *(const bf16x8_t*)&Vc[d * 128 + (((ks2 * 4 + quad) ^ (d & 7)) * 8)];
          }
        }
#pragma unroll
        for (int ni = 0; ni < 2; ni++) {
          int qr = ni * 16 + l16;
#pragma unroll
          for (int mm = 0; mm < 4; mm++) {
            bf16x4_t pk;
#pragma unroll
            for (int r = 0; r < 4; r++) pk[r] = (bf16)sacc[hh * 4 + mm][ni][r];
            int c = mm * 2 + (quad >> 1);
            *(bf16x4_t*)&Pw[qr * 64 + ((c ^ (qr & 7)) * 8) + (quad & 1) * 4] = pk;
          }
        }
#pragma unroll
        for (int k2 = 0; k2 < 2; k2++) {
          bf16x8_t pa[2];
#pragma unroll
          for (int ni = 0; ni < 2; ni++) {
            int qr = ni * 16 + l16;
            pa[ni] = *(const bf16x8_t*)&Pw[qr * 64 + (((k2 * 4 + quad) ^ (qr & 7)) * 8)];
          }
          __builtin_amdgcn_s_setprio(1);
#pragma unroll
          for (int mi = 0; mi < 4; mi++)
#pragma unroll
            for (int ni = 0; ni < 2; ni++)
              o[mi][ni] = __builtin_amdgcn_mfma_f32_16x16x32_bf16(vb[k2][mi], pa[ni], o[mi][ni], 0, 0, 0);
          __builtin_amdgcn_s_setprio(0);
        }
      }

      __syncthreads();  // one barrier/tile: drains vmcnt(0) (next tile staged) and
                        // guards buffer reuse for all waves
      cur ^= 1;
    }

    // epilogue: O^T lane layout -> O[b][s][h*64+d], packed 4 consecutive d
#pragma unroll
    for (int ni = 0; ni < 2; ni++) {
      float inv = 1.0f / l_[ni];
      int q_g = qb * 128 + wave * 32 + ni * 16 + l16;
      size_t rowb = (size_t)(b * S_ + q_g) * E_ + h * HD;
#pragma unroll
      for (int mi = 0; mi < 4; mi++) {
        bf16x4_t ov;
#pragma unroll
        for (int r = 0; r < 4; r++) ov[r] = (bf16)(o[mi][ni][r] * inv);
        *(bf16x4_t*)&O[rowb + mi * 16 + quad * 4] = ov;
      }
    }
  }
}

extern "C" void kernel_launch(void* const* d_in, const int* in_sizes, int n_in,
                              void* d_out, int out_size, void* d_ws, size_t ws_size,
                              hipStream_t stream) {
  const float* x      = (const float*)d_in[0];
  const float* W_attn = (const float*)d_in[1];
  const float* b_attn = (const float*)d_in[2];
  const float* W_proj = (const float*)d_in[3];
  const float* b_proj = (const float*)d_in[4];
  float* out = (float*)d_out;

  // workspace (bf16 elems), ~75.5 MB total
  bf16* xb  = (bf16*)d_ws;            // 8192*1024
  bf16* Wat = xb + 8388608ull;        // 3072*1024 (W_attn^T)
  bf16* Wpt = Wat + 3145728ull;       // 1024*1024 (W_proj^T)
  bf16* Qb  = Wpt + 1048576ull;       // [B,H,S,64], pre-scaled by QSCALE
  bf16* Kb  = Qb + 8388608ull;        // [B,H,S,64]
  bf16* Vtb = Kb + 8388608ull;        // [B,H,64,S] (written transposed by QKV epilogue)
  bf16* AOb = xb;                     // alias: x dead after QKV GEMM

  cvt4<<<8192, 256, 0, stream>>>(x, xb);
  transpose_cvt<<<dim3(96, 32), 256, 0, stream>>>(W_attn, Wat, 1024, 3072);
  transpose_cvt<<<dim3(32, 32), 256, 0, stream>>>(W_proj, Wpt, 1024, 1024);
  gemm128<0><<<dim3(64, 24), 256, 0, stream>>>(xb, Wat, b_attn, Qb, Kb, Vtb, nullptr);
  attn_kernel<<<dim3(8, 64), 256, 81920, stream>>>(Qb, Kb, Vtb, AOb);
  gemm128<1><<<dim3(64, 8), 256, 0, stream>>>(AOb, Wpt, b_proj, nullptr, nullptr, nullptr, out);
}

// Round 5
// 230.033 us; speedup vs baseline: 1.7688x; 1.0735x over previous
//
#include <hip/hip_runtime.h>

typedef __bf16 bf16;
typedef __bf16 bf16x8_t __attribute__((ext_vector_type(8)));
typedef __bf16 bf16x4_t __attribute__((ext_vector_type(4)));
typedef float f32x4_t __attribute__((ext_vector_type(4)));

#define S_ 2048
#define E_ 1024
#define HD 64
#define LOG2E 1.4426950408889634f
#define QSCALE (0.125f * LOG2E)   // 1/sqrt(64) * log2(e), folded into Q

// async global->LDS, 16B per lane; LDS dest is wave-uniform base + lane*16
__device__ __forceinline__ void gl_lds16(const bf16* g, bf16* l) {
  __builtin_amdgcn_global_load_lds(
      (const __attribute__((address_space(1))) unsigned int*)g,
      (__attribute__((address_space(3))) unsigned int*)l, 16, 0, 0);
}

// ---------- fused prep: x fp32->bf16, W_attn^T, W_proj^T (one launch) ----------
__device__ __forceinline__ void transpose_tile(const float* __restrict__ in,
                                               bf16* __restrict__ out,
                                               int R, int C, int bx, int by,
                                               float tile[32][33]) {
  int c0 = bx * 32, r0 = by * 32;
  int tx = threadIdx.x & 31, ty = threadIdx.x >> 5;
#pragma unroll
  for (int i = 0; i < 32; i += 8)
    tile[ty + i][tx] = in[(size_t)(r0 + ty + i) * C + c0 + tx];
  __syncthreads();
#pragma unroll
  for (int i = 0; i < 32; i += 8)
    out[(size_t)(c0 + ty + i) * R + r0 + tx] = (bf16)tile[tx][ty + i];
}

__global__ void prep(const float* __restrict__ x, bf16* __restrict__ xb,
                     const float* __restrict__ Wa, bf16* __restrict__ Wat,
                     const float* __restrict__ Wp, bf16* __restrict__ Wpt) {
  __shared__ float tile[32][33];
  int bid = blockIdx.x;
  if (bid < 8192) {                       // cvt: 8192*1024 fp32 -> bf16
    int i = (bid * 256 + threadIdx.x) * 4;
    float4 v = *(const float4*)(x + i);
    bf16x4_t o = { (bf16)v.x, (bf16)v.y, (bf16)v.z, (bf16)v.w };
    *(bf16x4_t*)(xb + i) = o;
  } else if (bid < 8192 + 3072) {         // W_attn [1024][3072] -> [3072][1024]
    int f = bid - 8192;
    transpose_tile(Wa, Wat, 1024, 3072, f % 96, f / 96, tile);
  } else {                                // W_proj [1024][1024] -> [1024][1024]^T
    int f = bid - 11264;
    transpose_tile(Wp, Wpt, 1024, 1024, f % 32, f / 32, tile);
  }
}

// ---------- 128x128-tile GEMM, BK=64, global_load_lds staging, XOR-swizzled LDS ----
// MODE 0: QKV epilogue (scatter to Q scaled, K, Vt transposed). MODE 1: proj fp32 out.
template <int MODE>
__global__ __launch_bounds__(256, 2)
void gemm128(const bf16* __restrict__ A, const bf16* __restrict__ Bt,
             const float* __restrict__ bias,
             bf16* __restrict__ Q, bf16* __restrict__ K, bf16* __restrict__ Vt,
             float* __restrict__ Out) {
  __shared__ __align__(16) bf16 As[128 * 64];
  __shared__ __align__(16) bf16 Bs[128 * 64];
  const int tid = threadIdx.x;
  const int wave = tid >> 6, lane = tid & 63;
  const int quad = lane >> 4, l16 = lane & 15;
  const int wm = wave >> 1, wn = wave & 1;
  const int bm = blockIdx.x, bn = blockIdx.y;

  f32x4_t acc[4][4];
#pragma unroll
  for (int i = 0; i < 4; i++)
#pragma unroll
    for (int j = 0; j < 4; j++) acc[i][j] = (f32x4_t){0.f, 0.f, 0.f, 0.f};

  for (int k0 = 0; k0 < 1024; k0 += 64) {
    __syncthreads();
    // stage 16KB A + 16KB B; swizzle source so LDS chunk (row, c) holds
    // global chunk (row, c ^ (row&7)) -> reads are 2-way max
#pragma unroll
    for (int it = 0; it < 4; it++) {
      int id = it * 256 + tid;
      int row = id >> 3, c = id & 7;
      int sc = (c ^ (row & 7)) * 8;
      gl_lds16(A + (size_t)(bm * 128 + row) * 1024 + k0 + sc, As + id * 8);
      gl_lds16(Bt + (size_t)(bn * 128 + row) * 1024 + k0 + sc, Bs + id * 8);
    }
    __syncthreads();
#pragma unroll
    for (int ks = 0; ks < 2; ks++) {
      bf16x8_t af[4], bfr[4];
#pragma unroll
      for (int i = 0; i < 4; i++) {
        int row = wm * 64 + i * 16 + l16;
        af[i] = *(const bf16x8_t*)&As[row * 64 + (((ks * 4 + quad) ^ (row & 7)) * 8)];
      }
#pragma unroll
      for (int j = 0; j < 4; j++) {
        int row = wn * 64 + j * 16 + l16;
        bfr[j] = *(const bf16x8_t*)&Bs[row * 64 + (((ks * 4 + quad) ^ (row & 7)) * 8)];
      }
#pragma unroll
      for (int i = 0; i < 4; i++)
#pragma unroll
        for (int j = 0; j < 4; j++)
          acc[i][j] = __builtin_amdgcn_mfma_f32_16x16x32_bf16(af[i], bfr[j], acc[i][j], 0, 0, 0);
    }
  }

  if (MODE == 0) {
    // n decides q/k/v. Q: [bh][s][64] scaled by QSCALE. K: [bh][s][64]. V: [bh][64][s].
#pragma unroll
    for (int j = 0; j < 4; j++) {
      int n_g = bn * 128 + wn * 64 + j * 16 + l16;
      float bv = bias[n_g];
      int which = n_g >> 10;
      int cc = n_g & 1023;
      int hh = cc >> 6, dd = cc & 63;
#pragma unroll
      for (int i = 0; i < 4; i++) {
        int m0 = bm * 128 + wm * 64 + i * 16 + quad * 4;
        int bb = m0 >> 11, ss0 = m0 & 2047;
        int bhn = bb * 16 + hh;
        if (which == 2) {
          bf16x4_t pk;
#pragma unroll
          for (int r = 0; r < 4; r++) pk[r] = (bf16)(acc[i][j][r] + bv);
          *(bf16x4_t*)&Vt[((size_t)bhn * 64 + dd) * 2048 + ss0] = pk;
        } else {
          bf16* dst = (which == 0) ? Q : K;
          float scl = (which == 0) ? QSCALE : 1.f;
#pragma unroll
          for (int r = 0; r < 4; r++)
            dst[((size_t)bhn * 2048 + ss0 + r) * 64 + dd] = (bf16)((acc[i][j][r] + bv) * scl);
        }
      }
    }
  } else {
#pragma unroll
    for (int j = 0; j < 4; j++) {
      int n_g = bn * 128 + wn * 64 + j * 16 + l16;
      float bv = bias[n_g];
#pragma unroll
      for (int i = 0; i < 4; i++) {
        int m0 = bm * 128 + wm * 64 + i * 16 + quad * 4;
#pragma unroll
        for (int r = 0; r < 4; r++)
          Out[(size_t)(m0 + r) * 1024 + n_g] = acc[i][j][r] + bv;
      }
    }
  }
}

// ---------- Flash attention, S^T formulation, software-pipelined ----------
// Round-1 structure (74.8us measured): 4 waves; K/V double-buffered in 80KB dynamic
// LDS (2 blocks/CU); stage(kb+1) issued BEFORE compute(kb); single __syncthreads per
// tile. Wave owns 32 q rows. S^T = K*Q^T; PV: O^T = Vt*P^T via 32x64 wave-private P
// slice (two k-halves). All LDS chunk-XOR-swizzled.
// Round-4 addition: T1 bijective XCD work-swizzle. HW blocks round-robin XCDs by
// linear id; remap so XCD x owns bh in [8x, 8x+8) with all 8 q-block workers ->
// per-bh K/V (512KB) stays L2-resident instead of being refetched by 8 XCDs.
__global__ __launch_bounds__(256, 2)
void attn_kernel(const bf16* __restrict__ Q, const bf16* __restrict__ K,
                 const bf16* __restrict__ Vt, bf16* __restrict__ O) {
  extern __shared__ __align__(16) bf16 smem[];
  bf16* Ks = smem;              // [2][128*64]  2x16KB  [k][d] swizzled
  bf16* Vs = smem + 16384;      // [2][64*128]  2x16KB  [d][s] swizzled
  bf16* Ps = smem + 32768;      // [4][32*64]   16KB    per-wave P[q][kloc] swizzled
  const int tid = threadIdx.x;
  const int wave = tid >> 6, lane = tid & 63;
  const int quad = lane >> 4, l16 = lane & 15;
  const int lin = blockIdx.y * 8 + blockIdx.x;        // hw dispatch order
  const int w = (lin & 7) * 64 + (lin >> 3);          // bijective (512 % 8 == 0)
  const int pid = w & 7, bh = w >> 3;
  const int b = bh >> 4, h = bh & 15;

  const bf16* Qg = Q + (size_t)bh * S_ * HD;
  const bf16* Kg = K + (size_t)bh * S_ * HD;
  const bf16* Vg = Vt + (size_t)bh * HD * S_;
  bf16* Pw = Ps + wave * 2048;

  auto stage = [&](int c, int kb) {
    const bf16* Ksrc = Kg + (size_t)kb * 128 * HD;
    const bf16* Vsrc = Vg + kb * 128;
    bf16* Kd = Ks + c * 8192;
    bf16* Vd = Vs + c * 8192;
#pragma unroll
    for (int it = 0; it < 4; it++) {
      int id = it * 256 + tid;
      {
        int row = id >> 3, cc = id & 7;
        gl_lds16(Ksrc + row * 64 + ((cc ^ (row & 7)) * 8), Kd + id * 8);
      }
      {
        int d = id >> 4, cc = id & 15;
        gl_lds16(Vsrc + (size_t)d * S_ + ((cc ^ (d & 7)) * 8), Vd + id * 8);
      }
    }
  };

  int cur = 0;
  stage(0, 0);  // prologue: tile 0

  for (int qi = 0; qi < 2; qi++) {
    const int qb = qi ? (15 - pid) : pid;
    // Q fragments (B-operand): n = q row (l16), k = d
    bf16x8_t qf[2][2];
#pragma unroll
    for (int ni = 0; ni < 2; ni++)
#pragma unroll
      for (int ks = 0; ks < 2; ks++)
        qf[ni][ks] = *(const bf16x8_t*)(Qg +
            (size_t)(qb * 128 + wave * 32 + ni * 16 + l16) * HD + ks * 32 + quad * 8);

    f32x4_t o[4][2];
#pragma unroll
    for (int mi = 0; mi < 4; mi++)
#pragma unroll
      for (int ni = 0; ni < 2; ni++) o[mi][ni] = (f32x4_t){0.f, 0.f, 0.f, 0.f};
    float m_[2] = {-1e30f, -1e30f}, l_[2] = {0.f, 0.f};

    if (qi == 0) __syncthreads();  // prologue stage complete (qi=1's tile 0 is
                                   // covered by qi=0's last end-of-iter barrier)

    for (int kb = 0; kb <= qb; kb++) {
      // issue next tile's loads FIRST -> in flight under the whole compute phase
      if (kb < qb) stage(cur ^ 1, kb + 1);
      else if (qi == 0) stage(cur ^ 1, 0);  // prefetch qi=1's tile 0 (qb-independent)

      const bf16* Kc = Ks + cur * 8192;
      const bf16* Vc = Vs + cur * 8192;

      // S^T = K · Q^T : lane holds S^T[k = mi*16+quad*4+r][q = ni*16+l16]
      f32x4_t sacc[8][2];
#pragma unroll
      for (int mi = 0; mi < 8; mi++)
#pragma unroll
        for (int ni = 0; ni < 2; ni++) sacc[mi][ni] = (f32x4_t){0.f, 0.f, 0.f, 0.f};
#pragma unroll
      for (int ks = 0; ks < 2; ks++)
#pragma unroll
        for (int mi = 0; mi < 8; mi++) {
          int kr = mi * 16 + l16;
          bf16x8_t kf = *(const bf16x8_t*)&Kc[kr * 64 + (((ks * 4 + quad) ^ (kr & 7)) * 8)];
          sacc[mi][0] = __builtin_amdgcn_mfma_f32_16x16x32_bf16(kf, qf[0][ks], sacc[mi][0], 0, 0, 0);
          sacc[mi][1] = __builtin_amdgcn_mfma_f32_16x16x32_bf16(kf, qf[1][ks], sacc[mi][1], 0, 0, 0);
        }

      if (kb == qb) {  // causal mask, block-local
#pragma unroll
        for (int mi = 0; mi < 8; mi++)
#pragma unroll
          for (int ni = 0; ni < 2; ni++) {
            int qrow = wave * 32 + ni * 16 + l16;
            int krow = mi * 16 + quad * 4;
#pragma unroll
            for (int r = 0; r < 4; r++)
              if (krow + r > qrow) sacc[mi][ni][r] = -1e30f;
          }
      }

      // online softmax (base-2; scale folded into Q). Stats per q = in-lane + 2 shuffles.
#pragma unroll
      for (int ni = 0; ni < 2; ni++) {
        float mx = sacc[0][ni][0];
#pragma unroll
        for (int mi = 0; mi < 8; mi++)
#pragma unroll
          for (int r = 0; r < 4; r++) mx = fmaxf(mx, sacc[mi][ni][r]);
        mx = fmaxf(mx, __shfl_xor(mx, 16));
        mx = fmaxf(mx, __shfl_xor(mx, 32));
        float mnew = fmaxf(m_[ni], mx);
        float alpha = __builtin_amdgcn_exp2f(m_[ni] - mnew);
        m_[ni] = mnew;
        float rs = 0.f;
#pragma unroll
        for (int mi = 0; mi < 8; mi++)
#pragma unroll
          for (int r = 0; r < 4; r++) {
            float p = __builtin_amdgcn_exp2f(sacc[mi][ni][r] - mnew);
            sacc[mi][ni][r] = p;
            rs += p;
          }
        rs += __shfl_xor(rs, 16);
        rs += __shfl_xor(rs, 32);
        l_[ni] = alpha * l_[ni] + rs;
#pragma unroll
        for (int mi = 0; mi < 4; mi++)
#pragma unroll
          for (int r = 0; r < 4; r++) o[mi][ni][r] *= alpha;
      }

      // PV in two k-halves through the 32x64 wave-private P buffer:
      //   write P[q][kloc= k-64*hh] for mi in {4hh..4hh+3}, then O^T += Vt·P^T for
      //   ks2 in {2hh, 2hh+1}. Wave-private LDS + in-order DS pipe -> no barriers.
#pragma unroll
      for (int hh = 0; hh < 2; hh++) {
#pragma unroll
        for (int ni = 0; ni < 2; ni++) {
          int qr = ni * 16 + l16;
#pragma unroll
          for (int mm = 0; mm < 4; mm++) {
            bf16x4_t pk;
#pragma unroll
            for (int r = 0; r < 4; r++) pk[r] = (bf16)sacc[hh * 4 + mm][ni][r];
            int c = mm * 2 + (quad >> 1);
            *(bf16x4_t*)&Pw[qr * 64 + ((c ^ (qr & 7)) * 8) + (quad & 1) * 4] = pk;
          }
        }
#pragma unroll
        for (int k2 = 0; k2 < 2; k2++) {
          int ks2 = hh * 2 + k2;
          bf16x8_t vb[4], pa[2];
#pragma unroll
          for (int mi = 0; mi < 4; mi++) {
            int d = mi * 16 + l16;
            vb[mi] = *(const bf16x8_t*)&Vc[d * 128 + (((ks2 * 4 + quad) ^ (d & 7)) * 8)];
          }
#pragma unroll
          for (int ni = 0; ni < 2; ni++) {
            int qr = ni * 16 + l16;
            pa[ni] = *(const bf16x8_t*)&Pw[qr * 64 + (((k2 * 4 + quad) ^ (qr & 7)) * 8)];
          }
#pragma unroll
          for (int mi = 0; mi < 4; mi++)
#pragma unroll
            for (int ni = 0; ni < 2; ni++)
              o[mi][ni] = __builtin_amdgcn_mfma_f32_16x16x32_bf16(vb[mi], pa[ni], o[mi][ni], 0, 0, 0);
        }
      }

      __syncthreads();  // one barrier/tile: drains vmcnt(0) (next tile staged) and
                        // guards buffer reuse for all waves
      cur ^= 1;
    }

    // epilogue: O^T lane layout -> O[b][s][h*64+d], packed 4 consecutive d
#pragma unroll
    for (int ni = 0; ni < 2; ni++) {
      float inv = 1.0f / l_[ni];
      int q_g = qb * 128 + wave * 32 + ni * 16 + l16;
      size_t rowb = (size_t)(b * S_ + q_g) * E_ + h * HD;
#pragma unroll
      for (int mi = 0; mi < 4; mi++) {
        bf16x4_t ov;
#pragma unroll
        for (int r = 0; r < 4; r++) ov[r] = (bf16)(o[mi][ni][r] * inv);
        *(bf16x4_t*)&O[rowb + mi * 16 + quad * 4] = ov;
      }
    }
  }
}

extern "C" void kernel_launch(void* const* d_in, const int* in_sizes, int n_in,
                              void* d_out, int out_size, void* d_ws, size_t ws_size,
                              hipStream_t stream) {
  const float* x      = (const float*)d_in[0];
  const float* W_attn = (const float*)d_in[1];
  const float* b_attn = (const float*)d_in[2];
  const float* W_proj = (const float*)d_in[3];
  const float* b_proj = (const float*)d_in[4];
  float* out = (float*)d_out;

  // workspace (bf16 elems), ~75.5 MB total
  bf16* xb  = (bf16*)d_ws;            // 8192*1024
  bf16* Wat = xb + 8388608ull;        // 3072*1024 (W_attn^T)
  bf16* Wpt = Wat + 3145728ull;       // 1024*1024 (W_proj^T)
  bf16* Qb  = Wpt + 1048576ull;       // [B,H,S,64], pre-scaled by QSCALE
  bf16* Kb  = Qb + 8388608ull;        // [B,H,S,64]
  bf16* Vtb = Kb + 8388608ull;        // [B,H,64,S] (written transposed by QKV epilogue)
  bf16* AOb = xb;                     // alias: x dead after QKV GEMM

  prep<<<12288, 256, 0, stream>>>(x, xb, W_attn, Wat, W_proj, Wpt);
  gemm128<0><<<dim3(64, 24), 256, 0, stream>>>(xb, Wat, b_attn, Qb, Kb, Vtb, nullptr);
  attn_kernel<<<dim3(8, 64), 256, 81920, stream>>>(Qb, Kb, Vtb, AOb);
  gemm128<1><<<dim3(64, 8), 256, 0, stream>>>(AOb, Wpt, b_proj, nullptr, nullptr, nullptr, out);
}